// Round 15
// baseline (183.028 us; speedup 1.0000x reference)
//
#include <hip/hip_runtime.h>
#include <hip/hip_bf16.h>

// ConvSelfAttentionModule: B=4, C=256, CQK=128, N=4096 (64x64), fp32 in/out.
// R23 = R13 (proven 174.3us best) + i-split k_fav (2 wgs/CU, ZERO duplicated
// work) + k_comb.
// R14 lesson: in-wg role specialization spills (register union of both
// roles). R9 lesson: TLP via duplicated QK is net-negative. The i-split is
// the duplication-free TLP: wgs (b,j0,ih=0/1) take disjoint i-halves ->
// disjoint Q/V/rinv reads and QK/exp/AV work (shared: 16KB K tile only).
// Per-wg body BYTE-IDENTICAL to R13's k_fav (same macros/sE/barriers; only
// wg-uniform base offsets + loop 64->32), epilogue writes f32 partial.
// k_comb: out = gamma*(p0+p1) + x (67MB, L3-hot). LDS 32KB + VGPR ~100 ->
// 2 wgs/CU co-reside: independent barrier groups overlap exp with AV-MFMA.
//   k_xsplit : x -> fragment-tiled f16 + fused W convert [R16 + wcvt]
//   k_proj   : register-direct projections, no LDS/barriers [R16]
//   k_rows   : QK^T + exp + partial row sums (widened, 128 j/wg) [R15/R8]
//   k_rsum   : rinv[b][i] = 1 / sum_j exp(S[i,j]) [R15]
//   k_fav    : fused recompute+AV, wave-split 2-tile, i-split (above)
//   k_comb   : combine partials + gamma + residual

typedef _Float16 f16;
typedef _Float16 f16x4v __attribute__((ext_vector_type(4)));
typedef _Float16 f16x8v __attribute__((ext_vector_type(8)));
typedef float f32x4v __attribute__((ext_vector_type(4)));

static __device__ __forceinline__ f32x4v mfma16(f16x8v a, f16x8v b, f32x4v c) {
  // A-frag m=lane&15,k=quad*8+e; B-frag n=lane&15,k=quad*8+e
  // D: col(n)=lane&15, row(m)=quad*4+reg
  return __builtin_amdgcn_mfma_f32_16x16x32_f16(a, b, c, 0, 0, 0);
}

// ---------------- kernel 0: x transpose -> fragment-tiled f16, + W convert ----------------
// xTf elem (t,c): b*1048576 + (t>>4)*4096 + (c>>5)*512 + ((c>>3)&3)*128
//                 + (t&15)*8 + (c&7)
// wT  elem (o,c): (o>>4)*4096 + (c>>5)*512 + ((c>>3)&3)*128 + (o&15)*8 + (c&7)
__global__ void k_xsplit(const float* __restrict__ x, f16* __restrict__ xh,
                         const float* __restrict__ wq, const float* __restrict__ bq,
                         const float* __restrict__ wk, const float* __restrict__ bk,
                         const float* __restrict__ wv, const float* __restrict__ bv,
                         f16* __restrict__ wh, float* __restrict__ bcat) {
  // fused W convert: linear wg ids 0..511 each convert one W row (no deps)
  int id = blockIdx.x + 64 * (blockIdx.y + 4 * blockIdx.z);
  if (id < 512) {
    int o = id, c = threadIdx.x;
    const float* wrow; float bias;
    if (o < 128)      { wrow = wq + (size_t)o * 256;         bias = bq[o]; }
    else if (o < 256) { wrow = wk + (size_t)(o - 128) * 256; bias = bk[o - 128]; }
    else              { wrow = wv + (size_t)(o - 256) * 256; bias = bv[o - 256]; }
    wh[(size_t)(o >> 4) * 4096 + (size_t)(c >> 5) * 512 +
       (size_t)((c >> 3) & 3) * 128 + (o & 15) * 8 + (c & 7)] = (f16)wrow[c];
    if (c == 0) bcat[o] = bias;
  }
  __shared__ float t[64][65];
  int b = blockIdx.z, c0 = blockIdx.y * 64, n0 = blockIdx.x * 64;
  int tx = threadIdx.x & 63, ty = threadIdx.x >> 6;
  const float* xb = x + ((size_t)b * 256 + c0) * 4096 + n0;
#pragma unroll
  for (int r = ty; r < 64; r += 4) t[r][tx] = xb[(size_t)r * 4096 + tx];
  __syncthreads();
  f16* xbb = xh + (size_t)b * 1048576;
#pragma unroll
  for (int k2 = 0; k2 < 2; k2++) {
    int id2 = k2 * 256 + threadIdx.x;
    int tok = id2 & 63, oct = id2 >> 6;        // oct = 8-channel group 0..7
    int tt = n0 + tok;
    f16x8v v;
#pragma unroll
    for (int e = 0; e < 8; e++) v[e] = (f16)t[oct * 8 + e][tok];
    size_t addr = (size_t)(tt >> 4) * 4096 +
                  (size_t)((c0 >> 5) + (oct >> 2)) * 512 +
                  (size_t)(oct & 3) * 128 + (tt & 15) * 8;
    *(f16x8v*)&xbb[addr] = v;
  }
}

// ---------------- kernel 1: projections, register-direct [R16] ----------------
__global__ void __launch_bounds__(512, 1)
k_proj(const f16* __restrict__ xh, const f16* __restrict__ wh,
       const float* __restrict__ bcat, f16* __restrict__ qT,
       f16* __restrict__ kT, f16* __restrict__ vT) {
  int ob = blockIdx.x, th = blockIdx.y, b = blockIdx.z;
  int tid = threadIdx.x, l = tid & 63, w = tid >> 6;
  int col = l & 15, quad = l >> 4;
  int tt = w & 3, oh = w >> 2;
  int OT0 = ob * 4 + oh * 2;                   // first of 2 resident o-tiles
  const f16* wtb = wh + (size_t)OT0 * 4096 + l * 8;
  f16x8v wb[2][8];
#pragma unroll
  for (int jt = 0; jt < 2; jt++)
#pragma unroll
    for (int ks = 0; ks < 8; ks++)
      wb[jt][ks] = *(const f16x8v*)(wtb + jt * 4096 + ks * 512);
  float bias0 = bcat[OT0 * 16 + col];
  float bias1 = bcat[OT0 * 16 + 16 + col];
  const f16* atb = xh + (size_t)b * 1048576 + (size_t)(th * 32 + tt) * 4096 + l * 8;
  f16x8v afA[8], afB[8];
#pragma unroll
  for (int ks = 0; ks < 8; ks++) afA[ks] = *(const f16x8v*)(atb + ks * 512);

#define PROJ_BODY(IT, AF, AN, PREF)                                            \
  {                                                                            \
    if (PREF) {                                                                \
      _Pragma("unroll") for (int ks = 0; ks < 8; ks++)                         \
        AN[ks] = *(const f16x8v*)(atb + (size_t)((IT) + 1) * 16384 + ks * 512);\
    }                                                                          \
    f32x4v s0 = {}, s1 = {};                                                   \
    _Pragma("unroll") for (int ks = 0; ks < 8; ks++) {                         \
      s0 = mfma16(AF[ks], wb[0][ks], s0);                                      \
      s1 = mfma16(AF[ks], wb[1][ks], s1);                                      \
    }                                                                          \
    int T = th * 32 + (IT) * 4 + tt;                                           \
    if (ob < 4) {                                                              \
      f16* dst = (ob < 2) ? qT : kT;                                           \
      _Pragma("unroll") for (int jt = 0; jt < 2; jt++) {                       \
        int o = OT0 * 16 + jt * 16 + col;                                      \
        int d = o & 127;                                                       \
        float bs = jt ? bias1 : bias0;                                         \
        size_t base = (size_t)b * 524288 + (size_t)T * 2048 +                  \
                      (size_t)(d >> 5) * 512 + (size_t)((d >> 3) & 3) * 128 +  \
                      (d & 7);                                                 \
        float sv0 = jt ? s1[0] : s0[0], sv1 = jt ? s1[1] : s0[1];              \
        float sv2 = jt ? s1[2] : s0[2], sv3 = jt ? s1[3] : s0[3];              \
        dst[base + (quad * 4 + 0) * 8] = (f16)(sv0 + bs);                      \
        dst[base + (quad * 4 + 1) * 8] = (f16)(sv1 + bs);                      \
        dst[base + (quad * 4 + 2) * 8] = (f16)(sv2 + bs);                      \
        dst[base + (quad * 4 + 3) * 8] = (f16)(sv3 + bs);                      \
      }                                                                        \
    } else {                                                                   \
      int i0 = T * 16 + quad * 4;                                              \
      size_t ibase = (size_t)b * 1048576 + (size_t)(i0 >> 5) * 512 +           \
                     (size_t)((i0 >> 3) & 3) * 128 + (i0 & 7);                 \
      _Pragma("unroll") for (int jt = 0; jt < 2; jt++) {                       \
        int c = OT0 * 16 + jt * 16 + col - 256;                                \
        float bs = jt ? bias1 : bias0;                                         \
        f16x4v pv;                                                             \
        _Pragma("unroll") for (int rg = 0; rg < 4; rg++)                       \
          pv[rg] = (f16)((jt ? s1[rg] : s0[rg]) + bs);                         \
        *(f16x4v*)&vT[ibase + (size_t)(c >> 4) * 65536 + (c & 15) * 8] = pv;   \
      }                                                                        \
    }                                                                          \
  }

  for (int itp = 0; itp < 4; itp++) {
    int itA = itp * 2;
    PROJ_BODY(itA, afA, afB, true)
    PROJ_BODY(itA + 1, afB, afA, itp < 3)
  }
#undef PROJ_BODY
}

// ---------------- kernel 2: row sums of exp(S), widened (128 j per wg) [R8] ----------------
__global__ void __launch_bounds__(512, 2)
k_rows(const f16* __restrict__ qT, const f16* __restrict__ kT,
       float* __restrict__ partial) {
  int jblk = blockIdx.x, ih = blockIdx.y, b = blockIdx.z;
  int tid = threadIdx.x, l = tid & 63, w = tid >> 6;
  int col = l & 15;
  int ti = w & 3, jh = w >> 2;
  const f16* ktb = kT + (size_t)b * 524288 + (size_t)(jblk * 8 + jh * 4) * 2048 + l * 8;
  const f16* qtb = qT + (size_t)b * 524288 + (size_t)ti * 2048 + l * 8;
  f16x8v ka[4][4];
#pragma unroll
  for (int jt = 0; jt < 4; jt++)
#pragma unroll
    for (int ks = 0; ks < 4; ks++)
      ka[jt][ks] = *(const f16x8v*)(ktb + jt * 2048 + ks * 512);
  float* pout = partial + ((size_t)(b * 32 + jblk) * 2 + jh) * 4096 + ti * 16 + col;
  int it0 = ih * 32;
  f16x8v qfA[4], qfB[4];
#pragma unroll
  for (int ks = 0; ks < 4; ks++)
    qfA[ks] = *(const f16x8v*)(qtb + (size_t)it0 * 8192 + ks * 512);

#define ROWS_BODY(IT, QF, QN, PREF)                                           \
  {                                                                           \
    if (PREF) {                                                               \
      _Pragma("unroll") for (int ks = 0; ks < 4; ks++)                        \
        QN[ks] = *(const f16x8v*)(qtb + (size_t)((IT) + 1) * 8192 + ks * 512);\
    }                                                                         \
    f32x4v s[4] = {};                                                         \
    _Pragma("unroll") for (int ks = 0; ks < 4; ks++) {                        \
      s[0] = mfma16(ka[0][ks], QF[ks], s[0]);                                 \
      s[1] = mfma16(ka[1][ks], QF[ks], s[1]);                                 \
      s[2] = mfma16(ka[2][ks], QF[ks], s[2]);                                 \
      s[3] = mfma16(ka[3][ks], QF[ks], s[3]);                                 \
    }                                                                         \
    float t = 0.f;                                                            \
    _Pragma("unroll") for (int jt = 0; jt < 4; jt++)                          \
      _Pragma("unroll") for (int rg = 0; rg < 4; rg++)                        \
        t += __expf(s[jt][rg]);                                               \
    t += __shfl_xor(t, 16);                                                   \
    t += __shfl_xor(t, 32);                                                   \
    if (l < 16) pout[(size_t)(IT) * 64] = t;                                  \
  }

  for (int itp = 0; itp < 16; itp++) {
    int itA = it0 + itp * 2;
    ROWS_BODY(itA, qfA, qfB, true)
    ROWS_BODY(itA + 1, qfB, qfA, itp < 15)
  }
#undef ROWS_BODY
}

// ---------------- kernel 3: combine partials -> rinv = 1/rowsum ----------------
__global__ void k_rsum(const float* __restrict__ partial, float* __restrict__ rinv) {
  int b = blockIdx.y;
  int i = blockIdx.x * 256 + threadIdx.x;
  const float* p = partial + (size_t)b * 64 * 4096 + i;
  float s = 0.f;
#pragma unroll 8
  for (int jb = 0; jb < 64; jb++) s += p[(size_t)jb * 4096];
  rinv[(size_t)b * 4096 + i] = 1.0f / s;
}

// ---------------- kernel 4: fused recompute + AV, wave-split, i-split ----------------
// wg (b, j0, ih): j-cols [j0,j0+64), i-tiles [ih*32, ih*32+32) — disjoint
// halves, NO duplicated work (K 16KB shared). Body = R13's proven wave-split
// 2-tile loop verbatim (local tile index 0..31); epilogue writes f32 partial
// pacc[ih][b][c][j]. 512 wgs, LDS 32KB, VGPR ~100 -> 2 wgs/CU: independent
// barrier groups overlap one wg's exp/VALU with the other's AV-MFMA.
__global__ void __launch_bounds__(512, 2)
k_fav(const f16* __restrict__ qT, const f16* __restrict__ kT,
      const f16* __restrict__ vT, const float* __restrict__ rinv,
      float* __restrict__ pacc) {
  __shared__ f16 sE[2][2][4096];  // [pair][tile][64 j][64 i], XOR(j&7) groups
  // XCD-chunked swizzle: 512 wgs, 8 XCDs -> contiguous 64-wg slice per XCD;
  // adjacent lg pairs share (b,j0) (differ in ih) -> shared K L2 lines.
  int wg = blockIdx.x;
  int lg = (wg & 7) * 64 + (wg >> 3);
  int b = lg >> 7;
  int rem = lg & 127;
  int j0 = (rem >> 1) * 64;
  int ih = rem & 1;
  int tid = threadIdx.x, l = tid & 63, w = tid >> 6;
  int col = l & 15, quad = l >> 4;
  int ti = w & 3, sel = w >> 2;
  const f16* ktb = kT + (size_t)b * 524288 + (size_t)(j0 / 16) * 2048 + l * 8;
  const f16* qtb = qT + (size_t)b * 524288 + (size_t)(ih * 32) * 8192 +
                   (size_t)ti * 2048 + l * 8;
  const f16* vtb = vT + (size_t)b * 1048576 + (size_t)(w * 2) * 65536 +
                   (size_t)(ih * 32) * 1024 + l * 8;
  const float* rp = rinv + (size_t)b * 4096 + ih * 2048 + ti * 16 + col;
  // K fragments: ALL 4 j-tiles resident (k_rows pattern, 64 VGPR)
  f16x8v ka[4][4];
#pragma unroll
  for (int jt = 0; jt < 4; jt++)
#pragma unroll
    for (int ks = 0; ks < 4; ks++)
      ka[jt][ks] = *(const f16x8v*)(ktb + jt * 2048 + ks * 512);
  f16x8v qf[4], vfA[2][2], vfB[2][2];
#pragma unroll
  for (int ks = 0; ks < 4; ks++)
    qf[ks] = *(const f16x8v*)(qtb + (size_t)sel * 8192 + ks * 512);
  float rv = rp[sel * 64];
  f32x4v acc[2][4] = {};
  int ig = ti * 2 + (col >> 3);
  int i_lo = col & 7;

#define FAV_WR(SJ, JT, P)                                                      \
  _Pragma("unroll") for (int rg = 0; rg < 4; rg++) {                           \
    int jl = (JT) * 16 + quad * 4 + rg;                                        \
    sE[P][sel][jl * 64 + ((ig ^ (jl & 7)) * 8) + i_lo] =                       \
        (f16)(__expf(SJ[rg]) * rv);                                            \
  }

#define FAV_AV(VF, P, SET)                                                     \
  {                                                                            \
    _Pragma("unroll") for (int ks = 0; ks < 2; ks++) {                         \
      int sw = ((ks * 4 + quad) ^ (col & 7)) * 8;                              \
      f16x8v e0 = *(const f16x8v*)&sE[P][SET][col * 64 + sw];                  \
      f16x8v e1 = *(const f16x8v*)&sE[P][SET][(16 + col) * 64 + sw];           \
      f16x8v e2 = *(const f16x8v*)&sE[P][SET][(32 + col) * 64 + sw];           \
      f16x8v e3 = *(const f16x8v*)&sE[P][SET][(48 + col) * 64 + sw];           \
      acc[0][0] = mfma16(VF[0][ks], e0, acc[0][0]);                            \
      acc[0][1] = mfma16(VF[0][ks], e1, acc[0][1]);                            \
      acc[0][2] = mfma16(VF[0][ks], e2, acc[0][2]);                            \
      acc[0][3] = mfma16(VF[0][ks], e3, acc[0][3]);                            \
      acc[1][0] = mfma16(VF[1][ks], e0, acc[1][0]);                            \
      acc[1][1] = mfma16(VF[1][ks], e1, acc[1][1]);                            \
      acc[1][2] = mfma16(VF[1][ks], e2, acc[1][2]);                            \
      acc[1][3] = mfma16(VF[1][ks], e3, acc[1][3]);                            \
    }                                                                          \
  }

  for (int s = 0; s < 16; s++) {
    int t0 = s * 2;        // local tile in [0,32)
    int p = s & 1;
    // V fragments, tile t0 (issue early; used after barrier)
#pragma unroll
    for (int mt = 0; mt < 2; mt++)
#pragma unroll
      for (int ks = 0; ks < 2; ks++)
        vfA[mt][ks] = *(const f16x8v*)(vtb + mt * 65536 + (size_t)(t0 * 2 + ks) * 512);
    // QK for this wave's tile (t0+sel): all 64 j
    f32x4v sj0 = {}, sj1 = {}, sj2 = {}, sj3 = {};
#pragma unroll
    for (int ks = 0; ks < 4; ks++) {
      sj0 = mfma16(ka[0][ks], qf[ks], sj0);
      sj1 = mfma16(ka[1][ks], qf[ks], sj1);
      sj2 = mfma16(ka[2][ks], qf[ks], sj2);
      sj3 = mfma16(ka[3][ks], qf[ks], sj3);
    }
    // V fragments, tile t0+1
#pragma unroll
    for (int mt = 0; mt < 2; mt++)
#pragma unroll
      for (int ks = 0; ks < 2; ks++)
        vfB[mt][ks] = *(const f16x8v*)(vtb + mt * 65536 + (size_t)(t0 * 2 + 2 + ks) * 512);
    if (p) { FAV_WR(sj0, 0, 1) FAV_WR(sj1, 1, 1) FAV_WR(sj2, 2, 1) FAV_WR(sj3, 3, 1) }
    else   { FAV_WR(sj0, 0, 0) FAV_WR(sj1, 1, 0) FAV_WR(sj2, 2, 0) FAV_WR(sj3, 3, 0) }
    asm volatile("s_waitcnt lgkmcnt(0)\n\ts_barrier" ::: "memory");
    if (s < 15) {
#pragma unroll
      for (int ks = 0; ks < 4; ks++)
        qf[ks] = *(const f16x8v*)(qtb + (size_t)(t0 + 2 + sel) * 8192 + ks * 512);
      rv = rp[(size_t)(t0 + 2 + sel) * 64];
    }
    if (p) { FAV_AV(vfA, 1, 0) FAV_AV(vfB, 1, 1) }
    else   { FAV_AV(vfA, 0, 0) FAV_AV(vfB, 0, 1) }
  }
#undef FAV_WR
#undef FAV_AV

  float* pD = pacc + (size_t)(ih * 4 + b) * 1048576;
#pragma unroll
  for (int mt = 0; mt < 2; mt++)
#pragma unroll
    for (int jt = 0; jt < 4; jt++) {
      int c = w * 32 + mt * 16 + quad * 4;
      int j = j0 + jt * 16 + col;
#pragma unroll
      for (int rg = 0; rg < 4; rg++)
        pD[(size_t)(c + rg) * 4096 + j] = acc[mt][jt][rg];
    }
}

// ---------------- kernel 5: combine partials + gamma + residual ----------------
// out = gamma*(p0+p1) + x over 16.8M floats (partials L3-hot).
__global__ void k_comb(const float* __restrict__ pacc, const float* __restrict__ x,
                       const float* __restrict__ gamma, float* __restrict__ out) {
  size_t f = ((size_t)blockIdx.x * 256 + threadIdx.x) * 4;
  float gm = gamma[0];
  f32x4v a = *(const f32x4v*)&pacc[f];
  f32x4v bb = *(const f32x4v*)&pacc[4194304 + f];
  f32x4v xv = *(const f32x4v*)&x[f];
  f32x4v o;
#pragma unroll
  for (int e = 0; e < 4; e++) o[e] = gm * (a[e] + bb[e]) + xv[e];
  *(f32x4v*)&out[f] = o;
}

extern "C" void kernel_launch(void* const* d_in, const int* in_sizes, int n_in,
                              void* d_out, int out_size, void* d_ws, size_t ws_size,
                              hipStream_t stream) {
  (void)in_sizes; (void)n_in; (void)out_size; (void)ws_size;
  const float* x  = (const float*)d_in[0];
  const float* wq = (const float*)d_in[1];
  const float* bq = (const float*)d_in[2];
  const float* wk = (const float*)d_in[3];
  const float* bk = (const float*)d_in[4];
  const float* wv = (const float*)d_in[5];
  const float* bv = (const float*)d_in[6];
  const float* gm = (const float*)d_in[7];
  float* out = (float*)d_out;

  char* ws = (char*)d_ws;
  f16*  xh = (f16*)ws;                          // 8 MB fragment-tiled x
  f16*  qT = (f16*)(ws + 8388608);              // 4 MB fragment-tiled Q
  f16*  kT = (f16*)(ws + 12582912);             // 4 MB fragment-tiled K
  f16*  vT = (f16*)(ws + 16777216);             // 8 MB fragment-tiled V
  f16*  wh = (f16*)(ws + 25165824);             // 256 KB fragment-tiled W
  float* bcat    = (float*)(ws + 25427968);     // 2 KB
  float* rinv    = (float*)(ws + 25430016);     // 64 KB
  float* partial = (float*)(ws + 25495552);     // 4 MB: [b][64][4096]
  float* pacc    = (float*)(ws + 33554432);     // 33.5 MB: [2][b][256][4096] f32

  hipLaunchKernelGGL(k_xsplit, dim3(64, 4, 4), dim3(256), 0, stream,
                     x, xh, wq, bq, wk, bk, wv, bv, wh, bcat);
  hipLaunchKernelGGL(k_proj, dim3(8, 8, 4), dim3(512), 0, stream, xh, wh, bcat, qT, kT, vT);
  hipLaunchKernelGGL(k_rows, dim3(32, 2, 4), dim3(512), 0, stream, qT, kT, partial);
  hipLaunchKernelGGL(k_rsum, dim3(16, 4), dim3(256), 0, stream, partial, rinv);
  hipLaunchKernelGGL(k_fav, dim3(512), dim3(512), 0, stream, qT, kT, vT, rinv, pacc);
  hipLaunchKernelGGL(k_comb, dim3(4096), dim3(256), 0, stream, pacc, x, gm, out);
}

// Round 16
// 176.414 us; speedup vs baseline: 1.0375x; 1.0375x over previous
//
#include <hip/hip_runtime.h>
#include <hip/hip_bf16.h>

// ConvSelfAttentionModule: B=4, C=256, CQK=128, N=4096 (64x64), fp32 in/out.
// R24 = R13 (proven 174.3us best) + packed-b64 sE writes in k_fav's QK phase.
// R15 lesson: k_fav is rigid ~62us across occupancy/traffic changes -> the
// binding pipe is LDS issue: 8 waves x 16 scalar ds_write_b16 (~740cyc) +
// reads (~770cyc) > MFMA (~930cyc). Fix: swap QK operands (mfma(qf,ka)) so
// each lane holds 4 CONSECUTIVE i at one j -> one f16x4 ds_write_b64; writes
// 16xb16 -> 4xb64 per wave per tile. Layout: logical i-group g=ti*2+(quad>>1)
// stored at g^(jl&7) — same convention as the existing read-side XOR, so AV
// reads byte-identical; bank analysis <=2-way (free). rinv -> per-lane f32x4.
// Barriers/roles/V-loads/AV/epilogue identical to R13. (R5's packed attempt
// failed on a conflicted layout + barrier restructure; neither repeated.)
//   k_xsplit : x -> fragment-tiled f16 + fused W convert [R16 + wcvt]
//   k_proj   : register-direct projections, no LDS/barriers [R16]
//   k_rows   : QK^T + exp + partial row sums (widened, 128 j/wg) [R15/R8]
//   k_rsum   : rinv[b][i] = 1 / sum_j exp(S[i,j]) [R15]
//   k_fav    : fused recompute+AV, wave-split 2-tile, packed sE writes

typedef _Float16 f16;
typedef _Float16 f16x4v __attribute__((ext_vector_type(4)));
typedef _Float16 f16x8v __attribute__((ext_vector_type(8)));
typedef float f32x4v __attribute__((ext_vector_type(4)));

static __device__ __forceinline__ f32x4v mfma16(f16x8v a, f16x8v b, f32x4v c) {
  // A-frag m=lane&15,k=quad*8+e; B-frag n=lane&15,k=quad*8+e
  // D: col(n)=lane&15, row(m)=quad*4+reg
  return __builtin_amdgcn_mfma_f32_16x16x32_f16(a, b, c, 0, 0, 0);
}

// ---------------- kernel 0: x transpose -> fragment-tiled f16, + W convert ----------------
// xTf elem (t,c): b*1048576 + (t>>4)*4096 + (c>>5)*512 + ((c>>3)&3)*128
//                 + (t&15)*8 + (c&7)
// wT  elem (o,c): (o>>4)*4096 + (c>>5)*512 + ((c>>3)&3)*128 + (o&15)*8 + (c&7)
__global__ void k_xsplit(const float* __restrict__ x, f16* __restrict__ xh,
                         const float* __restrict__ wq, const float* __restrict__ bq,
                         const float* __restrict__ wk, const float* __restrict__ bk,
                         const float* __restrict__ wv, const float* __restrict__ bv,
                         f16* __restrict__ wh, float* __restrict__ bcat) {
  // fused W convert: linear wg ids 0..511 each convert one W row (no deps)
  int id = blockIdx.x + 64 * (blockIdx.y + 4 * blockIdx.z);
  if (id < 512) {
    int o = id, c = threadIdx.x;
    const float* wrow; float bias;
    if (o < 128)      { wrow = wq + (size_t)o * 256;         bias = bq[o]; }
    else if (o < 256) { wrow = wk + (size_t)(o - 128) * 256; bias = bk[o - 128]; }
    else              { wrow = wv + (size_t)(o - 256) * 256; bias = bv[o - 256]; }
    wh[(size_t)(o >> 4) * 4096 + (size_t)(c >> 5) * 512 +
       (size_t)((c >> 3) & 3) * 128 + (o & 15) * 8 + (c & 7)] = (f16)wrow[c];
    if (c == 0) bcat[o] = bias;
  }
  __shared__ float t[64][65];
  int b = blockIdx.z, c0 = blockIdx.y * 64, n0 = blockIdx.x * 64;
  int tx = threadIdx.x & 63, ty = threadIdx.x >> 6;
  const float* xb = x + ((size_t)b * 256 + c0) * 4096 + n0;
#pragma unroll
  for (int r = ty; r < 64; r += 4) t[r][tx] = xb[(size_t)r * 4096 + tx];
  __syncthreads();
  f16* xbb = xh + (size_t)b * 1048576;
#pragma unroll
  for (int k2 = 0; k2 < 2; k2++) {
    int id2 = k2 * 256 + threadIdx.x;
    int tok = id2 & 63, oct = id2 >> 6;        // oct = 8-channel group 0..7
    int tt = n0 + tok;
    f16x8v v;
#pragma unroll
    for (int e = 0; e < 8; e++) v[e] = (f16)t[oct * 8 + e][tok];
    size_t addr = (size_t)(tt >> 4) * 4096 +
                  (size_t)((c0 >> 5) + (oct >> 2)) * 512 +
                  (size_t)(oct & 3) * 128 + (tt & 15) * 8;
    *(f16x8v*)&xbb[addr] = v;
  }
}

// ---------------- kernel 1: projections, register-direct [R16] ----------------
__global__ void __launch_bounds__(512, 1)
k_proj(const f16* __restrict__ xh, const f16* __restrict__ wh,
       const float* __restrict__ bcat, f16* __restrict__ qT,
       f16* __restrict__ kT, f16* __restrict__ vT) {
  int ob = blockIdx.x, th = blockIdx.y, b = blockIdx.z;
  int tid = threadIdx.x, l = tid & 63, w = tid >> 6;
  int col = l & 15, quad = l >> 4;
  int tt = w & 3, oh = w >> 2;
  int OT0 = ob * 4 + oh * 2;                   // first of 2 resident o-tiles
  const f16* wtb = wh + (size_t)OT0 * 4096 + l * 8;
  f16x8v wb[2][8];
#pragma unroll
  for (int jt = 0; jt < 2; jt++)
#pragma unroll
    for (int ks = 0; ks < 8; ks++)
      wb[jt][ks] = *(const f16x8v*)(wtb + jt * 4096 + ks * 512);
  float bias0 = bcat[OT0 * 16 + col];
  float bias1 = bcat[OT0 * 16 + 16 + col];
  const f16* atb = xh + (size_t)b * 1048576 + (size_t)(th * 32 + tt) * 4096 + l * 8;
  f16x8v afA[8], afB[8];
#pragma unroll
  for (int ks = 0; ks < 8; ks++) afA[ks] = *(const f16x8v*)(atb + ks * 512);

#define PROJ_BODY(IT, AF, AN, PREF)                                            \
  {                                                                            \
    if (PREF) {                                                                \
      _Pragma("unroll") for (int ks = 0; ks < 8; ks++)                         \
        AN[ks] = *(const f16x8v*)(atb + (size_t)((IT) + 1) * 16384 + ks * 512);\
    }                                                                          \
    f32x4v s0 = {}, s1 = {};                                                   \
    _Pragma("unroll") for (int ks = 0; ks < 8; ks++) {                         \
      s0 = mfma16(AF[ks], wb[0][ks], s0);                                      \
      s1 = mfma16(AF[ks], wb[1][ks], s1);                                      \
    }                                                                          \
    int T = th * 32 + (IT) * 4 + tt;                                           \
    if (ob < 4) {                                                              \
      f16* dst = (ob < 2) ? qT : kT;                                           \
      _Pragma("unroll") for (int jt = 0; jt < 2; jt++) {                       \
        int o = OT0 * 16 + jt * 16 + col;                                      \
        int d = o & 127;                                                       \
        float bs = jt ? bias1 : bias0;                                         \
        size_t base = (size_t)b * 524288 + (size_t)T * 2048 +                  \
                      (size_t)(d >> 5) * 512 + (size_t)((d >> 3) & 3) * 128 +  \
                      (d & 7);                                                 \
        float sv0 = jt ? s1[0] : s0[0], sv1 = jt ? s1[1] : s0[1];              \
        float sv2 = jt ? s1[2] : s0[2], sv3 = jt ? s1[3] : s0[3];              \
        dst[base + (quad * 4 + 0) * 8] = (f16)(sv0 + bs);                      \
        dst[base + (quad * 4 + 1) * 8] = (f16)(sv1 + bs);                      \
        dst[base + (quad * 4 + 2) * 8] = (f16)(sv2 + bs);                      \
        dst[base + (quad * 4 + 3) * 8] = (f16)(sv3 + bs);                      \
      }                                                                        \
    } else {                                                                   \
      int i0 = T * 16 + quad * 4;                                              \
      size_t ibase = (size_t)b * 1048576 + (size_t)(i0 >> 5) * 512 +           \
                     (size_t)((i0 >> 3) & 3) * 128 + (i0 & 7);                 \
      _Pragma("unroll") for (int jt = 0; jt < 2; jt++) {                       \
        int c = OT0 * 16 + jt * 16 + col - 256;                                \
        float bs = jt ? bias1 : bias0;                                         \
        f16x4v pv;                                                             \
        _Pragma("unroll") for (int rg = 0; rg < 4; rg++)                       \
          pv[rg] = (f16)((jt ? s1[rg] : s0[rg]) + bs);                         \
        *(f16x4v*)&vT[ibase + (size_t)(c >> 4) * 65536 + (c & 15) * 8] = pv;   \
      }                                                                        \
    }                                                                          \
  }

  for (int itp = 0; itp < 4; itp++) {
    int itA = itp * 2;
    PROJ_BODY(itA, afA, afB, true)
    PROJ_BODY(itA + 1, afB, afA, itp < 3)
  }
#undef PROJ_BODY
}

// ---------------- kernel 2: row sums of exp(S), widened (128 j per wg) [R8] ----------------
__global__ void __launch_bounds__(512, 2)
k_rows(const f16* __restrict__ qT, const f16* __restrict__ kT,
       float* __restrict__ partial) {
  int jblk = blockIdx.x, ih = blockIdx.y, b = blockIdx.z;
  int tid = threadIdx.x, l = tid & 63, w = tid >> 6;
  int col = l & 15;
  int ti = w & 3, jh = w >> 2;
  const f16* ktb = kT + (size_t)b * 524288 + (size_t)(jblk * 8 + jh * 4) * 2048 + l * 8;
  const f16* qtb = qT + (size_t)b * 524288 + (size_t)ti * 2048 + l * 8;
  f16x8v ka[4][4];
#pragma unroll
  for (int jt = 0; jt < 4; jt++)
#pragma unroll
    for (int ks = 0; ks < 4; ks++)
      ka[jt][ks] = *(const f16x8v*)(ktb + jt * 2048 + ks * 512);
  float* pout = partial + ((size_t)(b * 32 + jblk) * 2 + jh) * 4096 + ti * 16 + col;
  int it0 = ih * 32;
  f16x8v qfA[4], qfB[4];
#pragma unroll
  for (int ks = 0; ks < 4; ks++)
    qfA[ks] = *(const f16x8v*)(qtb + (size_t)it0 * 8192 + ks * 512);

#define ROWS_BODY(IT, QF, QN, PREF)                                           \
  {                                                                           \
    if (PREF) {                                                               \
      _Pragma("unroll") for (int ks = 0; ks < 4; ks++)                        \
        QN[ks] = *(const f16x8v*)(qtb + (size_t)((IT) + 1) * 8192 + ks * 512);\
    }                                                                         \
    f32x4v s[4] = {};                                                         \
    _Pragma("unroll") for (int ks = 0; ks < 4; ks++) {                        \
      s[0] = mfma16(ka[0][ks], QF[ks], s[0]);                                 \
      s[1] = mfma16(ka[1][ks], QF[ks], s[1]);                                 \
      s[2] = mfma16(ka[2][ks], QF[ks], s[2]);                                 \
      s[3] = mfma16(ka[3][ks], QF[ks], s[3]);                                 \
    }                                                                         \
    float t = 0.f;                                                            \
    _Pragma("unroll") for (int jt = 0; jt < 4; jt++)                          \
      _Pragma("unroll") for (int rg = 0; rg < 4; rg++)                        \
        t += __expf(s[jt][rg]);                                               \
    t += __shfl_xor(t, 16);                                                   \
    t += __shfl_xor(t, 32);                                                   \
    if (l < 16) pout[(size_t)(IT) * 64] = t;                                  \
  }

  for (int itp = 0; itp < 16; itp++) {
    int itA = it0 + itp * 2;
    ROWS_BODY(itA, qfA, qfB, true)
    ROWS_BODY(itA + 1, qfB, qfA, itp < 15)
  }
#undef ROWS_BODY
}

// ---------------- kernel 3: combine partials -> rinv = 1/rowsum ----------------
__global__ void k_rsum(const float* __restrict__ partial, float* __restrict__ rinv) {
  int b = blockIdx.y;
  int i = blockIdx.x * 256 + threadIdx.x;
  const float* p = partial + (size_t)b * 64 * 4096 + i;
  float s = 0.f;
#pragma unroll 8
  for (int jb = 0; jb < 64; jb++) s += p[(size_t)jb * 4096];
  rinv[(size_t)b * 4096 + i] = 1.0f / s;
}

// ---------------- kernel 4: fused recompute + AV, wave-split, packed writes ----------------
// Per wg: batch b, j-cols [j0,j0+64), all 256 c. Super-iter s (tiles 2s,
// 2s+1), pair p=s&1; wave (ti=w&3, sel=w>>2):
//   V loads for both tiles (used post-barrier)
//   QK for tile 2s+sel ONLY, SWAPPED operands mfma(qf, ka[jt]): lane holds
//     S[i=ti*16+quad*4+rg][j=jt*16+col] — 4 consecutive i at one j
//   exp*rinv4 -> ONE f16x4 ds_write_b64 per jt (4 writes, was 16 b16):
//     logical i-group g=ti*2+(quad>>1) stored at g^(jl&7), +(quad&1)*4 —
//     same convention as the read-side XOR; <=2-way banks
//   lgkmcnt(0); s_barrier   (one barrier per 2 tiles — R10/R13 structure)
//   prefetch Q(2s+2+sel), rv4  (overlaps AV)
//   AV both tiles (BYTE-IDENTICAL to R13: acc[2][4], V c-tiles w*2,w*2+1)
__global__ void __launch_bounds__(512, 1)
k_fav(const f16* __restrict__ qT, const f16* __restrict__ kT,
      const f16* __restrict__ vT, const float* __restrict__ rinv,
      const float* __restrict__ x, const float* __restrict__ gamma,
      float* __restrict__ out) {
  __shared__ f16 sE[2][2][4096];  // [pair][tile][64 j][64 i], XOR(j&7) groups
  // XCD-chunked swizzle: 256 wgs, 8 XCDs -> contiguous 32-wg slice per XCD.
  int wg = blockIdx.x;
  int lg = (wg & 7) * 32 + (wg >> 3);
  int b = lg >> 6, j0 = (lg & 63) * 64;
  int tid = threadIdx.x, l = tid & 63, w = tid >> 6;
  int col = l & 15, quad = l >> 4;
  int ti = w & 3, sel = w >> 2;
  const f16* ktb = kT + (size_t)b * 524288 + (size_t)(j0 / 16) * 2048 + l * 8;
  const f16* qtb = qT + (size_t)b * 524288 + (size_t)ti * 2048 + l * 8;
  const f16* vtb = vT + (size_t)b * 1048576 + (size_t)(w * 2) * 65536 + l * 8;
  const float* rp = rinv + (size_t)b * 4096 + ti * 16 + quad * 4;
  // K fragments: ALL 4 j-tiles resident (k_rows pattern, 64 VGPR)
  f16x8v ka[4][4];
#pragma unroll
  for (int jt = 0; jt < 4; jt++)
#pragma unroll
    for (int ks = 0; ks < 4; ks++)
      ka[jt][ks] = *(const f16x8v*)(ktb + jt * 2048 + ks * 512);
  f16x8v qf[4], vfA[2][2], vfB[2][2];
#pragma unroll
  for (int ks = 0; ks < 4; ks++)
    qf[ks] = *(const f16x8v*)(qtb + (size_t)sel * 8192 + ks * 512);
  f32x4v rv4 = *(const f32x4v*)(rp + sel * 64);
  f32x4v acc[2][4] = {};
  int swr = ((ti * 2 + (quad >> 1)) ^ (col & 7)) * 8 + (quad & 1) * 4;

#define FAV_WR(SJ, JT, P)                                                      \
  {                                                                            \
    f16x4v pv;                                                                 \
    _Pragma("unroll") for (int rg = 0; rg < 4; rg++)                           \
      pv[rg] = (f16)(__expf(SJ[rg]) * rv4[rg]);                                \
    *(f16x4v*)&sE[P][sel][((JT) * 16 + col) * 64 + swr] = pv;                  \
  }

#define FAV_AV(VF, P, SET)                                                     \
  {                                                                            \
    _Pragma("unroll") for (int ks = 0; ks < 2; ks++) {                         \
      int sw = ((ks * 4 + quad) ^ (col & 7)) * 8;                              \
      f16x8v e0 = *(const f16x8v*)&sE[P][SET][col * 64 + sw];                  \
      f16x8v e1 = *(const f16x8v*)&sE[P][SET][(16 + col) * 64 + sw];           \
      f16x8v e2 = *(const f16x8v*)&sE[P][SET][(32 + col) * 64 + sw];           \
      f16x8v e3 = *(const f16x8v*)&sE[P][SET][(48 + col) * 64 + sw];           \
      acc[0][0] = mfma16(VF[0][ks], e0, acc[0][0]);                            \
      acc[0][1] = mfma16(VF[0][ks], e1, acc[0][1]);                            \
      acc[0][2] = mfma16(VF[0][ks], e2, acc[0][2]);                            \
      acc[0][3] = mfma16(VF[0][ks], e3, acc[0][3]);                            \
      acc[1][0] = mfma16(VF[1][ks], e0, acc[1][0]);                            \
      acc[1][1] = mfma16(VF[1][ks], e1, acc[1][1]);                            \
      acc[1][2] = mfma16(VF[1][ks], e2, acc[1][2]);                            \
      acc[1][3] = mfma16(VF[1][ks], e3, acc[1][3]);                            \
    }                                                                          \
  }

  for (int s = 0; s < 32; s++) {
    int t0 = s * 2;
    int p = s & 1;
    // V fragments, tile t0 (issue early; used after barrier)
#pragma unroll
    for (int mt = 0; mt < 2; mt++)
#pragma unroll
      for (int ks = 0; ks < 2; ks++)
        vfA[mt][ks] = *(const f16x8v*)(vtb + mt * 65536 + (size_t)(t0 * 2 + ks) * 512);
    // QK for this wave's tile (t0+sel), swapped operands: lane = 4 consec i
    f32x4v sj0 = {}, sj1 = {}, sj2 = {}, sj3 = {};
#pragma unroll
    for (int ks = 0; ks < 4; ks++) {
      sj0 = mfma16(qf[ks], ka[0][ks], sj0);
      sj1 = mfma16(qf[ks], ka[1][ks], sj1);
      sj2 = mfma16(qf[ks], ka[2][ks], sj2);
      sj3 = mfma16(qf[ks], ka[3][ks], sj3);
    }
    // V fragments, tile t0+1
#pragma unroll
    for (int mt = 0; mt < 2; mt++)
#pragma unroll
      for (int ks = 0; ks < 2; ks++)
        vfB[mt][ks] = *(const f16x8v*)(vtb + mt * 65536 + (size_t)(t0 * 2 + 2 + ks) * 512);
    if (p) { FAV_WR(sj0, 0, 1) FAV_WR(sj1, 1, 1) FAV_WR(sj2, 2, 1) FAV_WR(sj3, 3, 1) }
    else   { FAV_WR(sj0, 0, 0) FAV_WR(sj1, 1, 0) FAV_WR(sj2, 2, 0) FAV_WR(sj3, 3, 0) }
    asm volatile("s_waitcnt lgkmcnt(0)\n\ts_barrier" ::: "memory");
    if (s < 31) {
#pragma unroll
      for (int ks = 0; ks < 4; ks++)
        qf[ks] = *(const f16x8v*)(qtb + (size_t)(t0 + 2 + sel) * 8192 + ks * 512);
      rv4 = *(const f32x4v*)(rp + (size_t)(t0 + 2 + sel) * 64);
    }
    if (p) { FAV_AV(vfA, 1, 0) FAV_AV(vfB, 1, 1) }
    else   { FAV_AV(vfA, 0, 0) FAV_AV(vfB, 0, 1) }
  }
#undef FAV_WR
#undef FAV_AV

  float gm = gamma[0];
  const float* xb = x + (size_t)b * 256 * 4096;
  float* ob = out + (size_t)b * 256 * 4096;
#pragma unroll
  for (int mt = 0; mt < 2; mt++)
#pragma unroll
    for (int jt = 0; jt < 4; jt++) {
      int c = w * 32 + mt * 16 + quad * 4;
      int j = j0 + jt * 16 + col;
#pragma unroll
      for (int rg = 0; rg < 4; rg++) {
        size_t off = (size_t)(c + rg) * 4096 + j;
        ob[off] = gm * acc[mt][jt][rg] + xb[off];
      }
    }
}

extern "C" void kernel_launch(void* const* d_in, const int* in_sizes, int n_in,
                              void* d_out, int out_size, void* d_ws, size_t ws_size,
                              hipStream_t stream) {
  (void)in_sizes; (void)n_in; (void)out_size; (void)ws_size;
  const float* x  = (const float*)d_in[0];
  const float* wq = (const float*)d_in[1];
  const float* bq = (const float*)d_in[2];
  const float* wk = (const float*)d_in[3];
  const float* bk = (const float*)d_in[4];
  const float* wv = (const float*)d_in[5];
  const float* bv = (const float*)d_in[6];
  const float* gm = (const float*)d_in[7];
  float* out = (float*)d_out;

  char* ws = (char*)d_ws;
  f16*  xh = (f16*)ws;                          // 8 MB fragment-tiled x
  f16*  qT = (f16*)(ws + 8388608);              // 4 MB fragment-tiled Q
  f16*  kT = (f16*)(ws + 12582912);             // 4 MB fragment-tiled K
  f16*  vT = (f16*)(ws + 16777216);             // 8 MB fragment-tiled V
  f16*  wh = (f16*)(ws + 25165824);             // 256 KB fragment-tiled W
  float* bcat    = (float*)(ws + 25427968);     // 2 KB
  float* rinv    = (float*)(ws + 25430016);     // 64 KB
  float* partial = (float*)(ws + 25495552);     // 4 MB: [b][64][4096]

  hipLaunchKernelGGL(k_xsplit, dim3(64, 4, 4), dim3(256), 0, stream,
                     x, xh, wq, bq, wk, bk, wv, bv, wh, bcat);
  hipLaunchKernelGGL(k_proj, dim3(8, 8, 4), dim3(512), 0, stream, xh, wh, bcat, qT, kT, vT);
  hipLaunchKernelGGL(k_rows, dim3(32, 2, 4), dim3(512), 0, stream, qT, kT, partial);
  hipLaunchKernelGGL(k_rsum, dim3(16, 4), dim3(256), 0, stream, partial, rinv);
  hipLaunchKernelGGL(k_fav, dim3(256), dim3(512), 0, stream, qT, kT, vT, rinv, x, gm, out);
}